// Round 5
// baseline (929.713 us; speedup 1.0000x reference)
//
#include <hip/hip_runtime.h>
#include <hip/hip_bf16.h>

typedef __attribute__((ext_vector_type(8))) short bf16x8;
typedef __attribute__((ext_vector_type(4))) short s16x4;
typedef __attribute__((ext_vector_type(4))) float f32x4;

#define E_N      32768
#define N_DST_N  5000
#define NCLS     10

// ---- workspace layout (bytes) ----
#define OFF_HAGG   0            // f32 [5000][128]
#define OFF_POOL   2560000      // bf16 [32768][128]
#define OFF_WPACK  10948608     // bf16 packed fragments, 233472 elems

// packed-weight offsets in bf16x8 (8-elem) units
#define PK_QKV(l)  ((l) * 6144)
#define PK_WO(l)   (12288 + (l) * 2048)
#define PK_W1(l)   (16384 + (l) * 2048)
#define PK_W2(l)   (20480 + (l) * 2048)
#define PK_WEOUT   24576
#define PK_WEIN    28672

// HW bf16 converts (RNE). m240: casts lower efficiently; don't hand-write asm.
__device__ __forceinline__ unsigned short f2bf(float f) {
    __hip_bfloat16 h = __float2bfloat16(f);
    unsigned short u;
    __builtin_memcpy(&u, &h, 2);
    return u;
}
__device__ __forceinline__ unsigned int f2bf2(float lo, float hi) {
    __hip_bfloat162 h = __float22bfloat162_rn(make_float2(lo, hi));
    unsigned int u;
    __builtin_memcpy(&u, &h, 4);
    return u;
}

// ---------------------------------------------------------------------------
// Pack weights into bf16 B-fragment order:
// dst[((t*(K/32)+kk)*64 + lane)*8 + j] = W[k][n],
//   n = t*16 + (lane&15), k = kk*32 + (lane>>4)*8 + j.
// W_ein packed in a K=32 frame with zeros for k>=16.
// ---------------------------------------------------------------------------
__global__ void pack_weights(const float* __restrict__ Wqkv,
                             const float* __restrict__ Wo,
                             const float* __restrict__ W1,
                             const float* __restrict__ W2,
                             const float* __restrict__ W_eout,
                             const float* __restrict__ W_ein,
                             unsigned short* __restrict__ wpack) {
    int gid = blockIdx.x * 256 + threadIdx.x;
    if (gid >= 233472) return;
    if (gid >= 229376) {                     // W_ein section (K=16 padded to 32)
        int li = gid - 229376;
        int j = li & 7, lane = (li >> 3) & 63, t = li >> 9;
        int k = ((lane >> 4) << 3) + j;
        int n = t * 16 + (lane & 15);
        wpack[gid] = (k < 16) ? f2bf(W_ein[k * 128 + n]) : (unsigned short)0;
        return;
    }
    int id = gid;
    const float* src; int K, N, li;
    if (id < 98304)       { src = Wqkv + (id / 49152) * 49152; li = id % 49152; K = 128; N = 384; }
    else if (id < 131072) { id -= 98304;  src = Wo + (id / 16384) * 16384; li = id % 16384; K = 128; N = 128; }
    else if (id < 163840) { id -= 131072; src = W1 + (id / 16384) * 16384; li = id % 16384; K = 128; N = 128; }
    else if (id < 196608) { id -= 163840; src = W2 + (id / 16384) * 16384; li = id % 16384; K = 128; N = 128; }
    else                  { li = id - 196608; src = W_eout; K = 256; N = 128; }
    int j = li & 7, lane = (li >> 3) & 63, rest = li >> 9;
    int ks = K >> 5;
    int kk = rest % ks, t = rest / ks;
    int k = kk * 32 + ((lane >> 4) << 3) + j;
    int n = t * 16 + (lane & 15);
    wpack[gid] = f2bf(src[k * N + n]);
}

// ---------------------------------------------------------------------------
// LayerNorm over register residual (C-layout). Thread owns cols
// cA=w*32+c16, cB=cA+16, rows {rt*16 + row4 + r}. In-wave shfl reduce over
// c16, cross-wave via psum/psq partial tables. Writes bf16 a_bf mirror.
// Contains one internal __syncthreads (all threads must call).
// ---------------------------------------------------------------------------
__device__ __forceinline__ void layer_norm_reg(
    float res[2][2][4],
    const float gcol[2], const float bcol[2],
    unsigned short (*a_bf)[136],
    float (*psum)[4], float (*psq)[4],
    int w, int c16, int row4)
{
    float sv[2][4], qv[2][4];
#pragma unroll
    for (int rt = 0; rt < 2; ++rt)
#pragma unroll
        for (int r = 0; r < 4; ++r) {
            float x0 = res[rt][0][r], x1 = res[rt][1][r];
            float s = x0 + x1;
            float q = x0 * x0 + x1 * x1;
#pragma unroll
            for (int d = 1; d < 16; d <<= 1) {
                s += __shfl_xor(s, d);
                q += __shfl_xor(q, d);
            }
            sv[rt][r] = s; qv[rt][r] = q;
        }
    if (c16 == 0) {
#pragma unroll
        for (int rt = 0; rt < 2; ++rt)
#pragma unroll
            for (int r = 0; r < 4; ++r) {
                int row = rt * 16 + row4 + r;
                psum[row][w] = sv[rt][r];
                psq[row][w]  = qv[rt][r];
            }
    }
    __syncthreads();
#pragma unroll
    for (int rt = 0; rt < 2; ++rt)
#pragma unroll
        for (int r = 0; r < 4; ++r) {
            int row = rt * 16 + row4 + r;
            float4 S = *(const float4*)&psum[row][0];
            float4 Q = *(const float4*)&psq[row][0];
            float sum = (S.x + S.y) + (S.z + S.w);
            float sq  = (Q.x + Q.y) + (Q.z + Q.w);
            float mu  = sum * (1.f / 128.f);
            float var = sq * (1.f / 128.f) - mu * mu;
            float inv = rsqrtf(var + 1e-5f);
#pragma unroll
            for (int ti = 0; ti < 2; ++ti) {
                float y = (res[rt][ti][r] - mu) * inv * gcol[ti] + bcol[ti];
                res[rt][ti][r] = y;
                a_bf[row][w * 32 + ti * 16 + c16] = f2bf(y);
            }
        }
}

// ---------------------------------------------------------------------------
// Edge mega-kernel: one block (4 waves) per TWO edges. All matmuls AND
// attention on MFMA; residual stream in registers; LN via shfl+partials.
// LDS 30.0 KB -> 5 blocks/CU.
// ---------------------------------------------------------------------------
__global__ __launch_bounds__(256, 5) void edge_kernel(
    const float* __restrict__ edge_features,   // [E,16,15]
    const float* __restrict__ seq_times,       // [E,16]
    const int*   __restrict__ e_len,
    const float* __restrict__ b_ein,
    const float* __restrict__ bqkv,  const float* __restrict__ bo,
    const float* __restrict__ ln1_g, const float* __restrict__ ln1_b,
    const float* __restrict__ b1,    const float* __restrict__ b2,
    const float* __restrict__ ln2_g, const float* __restrict__ ln2_b,
    const unsigned short* __restrict__ wpack,
    unsigned short* __restrict__ pooled)       // [E,128] bf16
{
    __shared__ __align__(16) unsigned short a_bf[32][136];  // LN-out / Q / ctx
    __shared__ __align__(16) unsigned short k_bf[32][136];  // K
    __shared__ __align__(16) union VX {                     // x_bf dead after embed
        unsigned short vT[2][128][24];                      // V transposed [d][s]
        unsigned short x_bf[32][40];                        // input, cols16..31 = 0
    } vx;
    __shared__ __align__(16) float psum[32][4];
    __shared__ __align__(16) float psq[32][4];

    const int tid  = threadIdx.x;
    const int e0   = blockIdx.x * 2;
    const int lane = tid & 63;
    const int w    = tid >> 6;
    const int c16  = lane & 15;
    const int g    = lane >> 4;
    const int row4 = g << 2;
    const int kblk = g << 3;
    const int len0 = e_len[e0];
    const int len1 = e_len[e0 + 1];
    const f32x4 z4 = {0.f, 0.f, 0.f, 0.f};

    float res[2][2][4];          // [edge rt][col ti][row r]

    // LN params for this thread's two columns
    float lnG[2][2][2], lnB[2][2][2];    // [layer][ln#][ti]
#pragma unroll
    for (int l = 0; l < 2; ++l)
#pragma unroll
        for (int ti = 0; ti < 2; ++ti) {
            int col = w * 32 + ti * 16 + c16;
            lnG[l][0][ti] = ln1_g[l * 128 + col];
            lnB[l][0][ti] = ln1_b[l * 128 + col];
            lnG[l][1][ti] = ln2_g[l * 128 + col];
            lnB[l][1][ti] = ln2_b[l * 128 + col];
        }

    // ---- stage input (cols 16..31 zeroed for K=32 padding) ----
    for (int idx = tid; idx < 1024; idx += 256) {
        int r = idx >> 5, cc = idx & 31;
        int e = r >> 4, s = r & 15;
        float v = 0.f;
        if (cc < 15)       v = edge_features[(e0 + e) * 240 + s * 15 + cc];
        else if (cc == 15) v = seq_times[(e0 + e) * 16 + s];
        vx.x_bf[r][cc] = f2bf(v);
    }
    __syncthreads();

    const bf16x8* WP = (const bf16x8*)wpack;

    // ---- embed: relu(x @ W_ein + b) via MFMA (K=16 padded to 32) ----
    {
        bf16x8 axf[2];
#pragma unroll
        for (int rt = 0; rt < 2; ++rt)
            axf[rt] = *(const bf16x8*)&vx.x_bf[rt * 16 + c16][kblk];
#pragma unroll
        for (int ti = 0; ti < 2; ++ti) {
            bf16x8 bw = WP[PK_WEIN + (2 * w + ti) * 64 + lane];
            int col = (2 * w + ti) * 16 + c16;
            float bias = b_ein[col];
#pragma unroll
            for (int rt = 0; rt < 2; ++rt) {
                f32x4 acc = __builtin_amdgcn_mfma_f32_16x16x32_bf16(axf[rt], bw, z4, 0, 0, 0);
#pragma unroll
                for (int r = 0; r < 4; ++r) {
                    float v = fmaxf(acc[r] + bias, 0.f);
                    res[rt][ti][r] = v;
                    a_bf[rt * 16 + row4 + r][col] = f2bf(v);
                }
            }
        }
    }
    __syncthreads();

    for (int l = 0; l < 2; ++l) {
        // ---- QKV: Q -> a_bf (reuse), K -> k_bf, V -> vT (transposed) ----
        {
            bf16x8 af[2][4];
#pragma unroll
            for (int rt = 0; rt < 2; ++rt)
#pragma unroll
                for (int kk = 0; kk < 4; ++kk)
                    af[rt][kk] = *(const bf16x8*)&a_bf[rt * 16 + c16][kk * 32 + kblk];
            __syncthreads();   // all af reads done before Q overwrites a_bf
            const bf16x8* B = WP + PK_QKV(l);
#pragma unroll
            for (int seg = 0; seg < 3; ++seg) {
                bf16x8 bq[2][4];
#pragma unroll
                for (int ti = 0; ti < 2; ++ti)
#pragma unroll
                    for (int kk = 0; kk < 4; ++kk)
                        bq[ti][kk] = B[((seg * 8 + 2 * w + ti) * 4 + kk) * 64 + lane];
#pragma unroll
                for (int ti = 0; ti < 2; ++ti) {
                    int col = (2 * w + ti) * 16 + c16;
                    float bias = bqkv[l * 384 + seg * 128 + col];
#pragma unroll
                    for (int rt = 0; rt < 2; ++rt) {
                        f32x4 acc = z4;
#pragma unroll
                        for (int kk = 0; kk < 4; ++kk)
                            acc = __builtin_amdgcn_mfma_f32_16x16x32_bf16(
                                af[rt][kk], bq[ti][kk], acc, 0, 0, 0);
                        if (seg == 0) {
#pragma unroll
                            for (int r = 0; r < 4; ++r)
                                a_bf[rt * 16 + row4 + r][col] = f2bf(acc[r] + bias);
                        } else if (seg == 1) {
#pragma unroll
                            for (int r = 0; r < 4; ++r)
                                k_bf[rt * 16 + row4 + r][col] = f2bf(acc[r] + bias);
                        } else {
                            union { unsigned int u[2]; s16x4 v; } pk;
                            pk.u[0] = f2bf2(acc[0] + bias, acc[1] + bias);
                            pk.u[1] = f2bf2(acc[2] + bias, acc[3] + bias);
                            *(s16x4*)&vx.vT[rt][col][row4] = pk.v;   // V^T[d][s]
                        }
                    }
                }
            }
        }
        __syncthreads();

        // ---- attention via MFMA: S^T = K@Q^T, ctx^T = V^T@P^T ----
#pragma unroll
        for (int i = 0; i < 4; ++i) {
            int pp = w * 4 + i;
            int e  = pp >> 3;
            int hb = (pp & 7) * 16;
            int er = e * 16;
            int len = e ? len1 : len0;
            bf16x8 kf = {0,0,0,0,0,0,0,0};
            bf16x8 qf = {0,0,0,0,0,0,0,0};
            bf16x8 vf = {0,0,0,0,0,0,0,0};
            if (lane < 32) {   // dh = kblk+j < 16 only
                kf = *(const bf16x8*)&k_bf[er + c16][hb + kblk];
                qf = *(const bf16x8*)&a_bf[er + c16][hb + kblk];
                vf = *(const bf16x8*)&vx.vT[e][hb + c16][kblk];
            }
            f32x4 st = __builtin_amdgcn_mfma_f32_16x16x32_bf16(kf, qf, z4, 0, 0, 0);
            // lane holds S^T[k=4g+r][q=c16]
            float sv[4]; float mx = -1e30f;
#pragma unroll
            for (int r = 0; r < 4; ++r) {
                sv[r] = st[r] * 0.25f;
                if (4 * g + r < len) mx = fmaxf(mx, sv[r]);
            }
            mx = fmaxf(mx, __shfl_xor(mx, 16));
            mx = fmaxf(mx, __shfl_xor(mx, 32));
            float p[4]; float sum = 0.f;
#pragma unroll
            for (int r = 0; r < 4; ++r) {
                float pe = (4 * g + r < len) ? __expf(sv[r] - mx) : 0.f;
                p[r] = pe; sum += pe;
            }
            sum += __shfl_xor(sum, 16);
            sum += __shfl_xor(sum, 32);
            float inv = __fdividef(1.f, sum);
            unsigned int own0 = f2bf2(p[0] * inv, p[1] * inv);
            unsigned int own1 = f2bf2(p[2] * inv, p[3] * inv);
            // regroup P^T (C-layout, 4 k/lane) into B-frag layout (8 k/lane)
            unsigned int t0a = (unsigned int)__shfl((int)own0, (lane + 16) & 63);
            unsigned int t1a = (unsigned int)__shfl((int)own1, (lane + 16) & 63);
            unsigned int t0b = (unsigned int)__shfl((int)own0, (lane + 32) & 63);
            unsigned int t1b = (unsigned int)__shfl((int)own1, (lane + 32) & 63);
            union { unsigned int u[4]; bf16x8 v; } pb;
            if (g == 0)      { pb.u[0] = own0; pb.u[1] = own1; pb.u[2] = t0a; pb.u[3] = t1a; }
            else if (g == 1) { pb.u[0] = t0a;  pb.u[1] = t1a;  pb.u[2] = t0b; pb.u[3] = t1b; }
            else             { pb.u[0] = 0; pb.u[1] = 0; pb.u[2] = 0; pb.u[3] = 0; }
            f32x4 ct = __builtin_amdgcn_mfma_f32_16x16x32_bf16(vf, pb.v, z4, 0, 0, 0);
            // lane holds ctx^T[d=4g+r][q=c16] -> a_bf[er+q][hb+4g+r]
            union { unsigned int u[2]; s16x4 v; } cpk;
            cpk.u[0] = f2bf2(ct[0], ct[1]);
            cpk.u[1] = f2bf2(ct[2], ct[3]);
            *(s16x4*)&a_bf[er + c16][hb + 4 * g] = cpk.v;
        }
        __syncthreads();

        // ---- proj + residual (registers) ----
        {
            bf16x8 af[2][4];
#pragma unroll
            for (int rt = 0; rt < 2; ++rt)
#pragma unroll
                for (int kk = 0; kk < 4; ++kk)
                    af[rt][kk] = *(const bf16x8*)&a_bf[rt * 16 + c16][kk * 32 + kblk];
            const bf16x8* B = WP + PK_WO(l);
            bf16x8 bw[2][4];
#pragma unroll
            for (int ti = 0; ti < 2; ++ti)
#pragma unroll
                for (int kk = 0; kk < 4; ++kk)
                    bw[ti][kk] = B[((2 * w + ti) * 4 + kk) * 64 + lane];
#pragma unroll
            for (int ti = 0; ti < 2; ++ti) {
                int col = (2 * w + ti) * 16 + c16;
                float bias = bo[l * 128 + col];
#pragma unroll
                for (int rt = 0; rt < 2; ++rt) {
                    f32x4 acc = z4;
#pragma unroll
                    for (int kk = 0; kk < 4; ++kk)
                        acc = __builtin_amdgcn_mfma_f32_16x16x32_bf16(
                            af[rt][kk], bw[ti][kk], acc, 0, 0, 0);
#pragma unroll
                    for (int r = 0; r < 4; ++r)
                        res[rt][ti][r] += acc[r] + bias;
                }
            }
        }
        layer_norm_reg(res, lnG[l][0], lnB[l][0], a_bf, psum, psq, w, c16, row4);
        __syncthreads();

        // ---- FF1: relu(e @ W1 + b1) -> a_bf ----
        {
            bf16x8 af[2][4];
#pragma unroll
            for (int rt = 0; rt < 2; ++rt)
#pragma unroll
                for (int kk = 0; kk < 4; ++kk)
                    af[rt][kk] = *(const bf16x8*)&a_bf[rt * 16 + c16][kk * 32 + kblk];
            const bf16x8* B = WP + PK_W1(l);
            bf16x8 bw[2][4];
#pragma unroll
            for (int ti = 0; ti < 2; ++ti)
#pragma unroll
                for (int kk = 0; kk < 4; ++kk)
                    bw[ti][kk] = B[((2 * w + ti) * 4 + kk) * 64 + lane];
            f32x4 acc2[2][2];
#pragma unroll
            for (int ti = 0; ti < 2; ++ti)
#pragma unroll
                for (int rt = 0; rt < 2; ++rt) {
                    f32x4 acc = z4;
#pragma unroll
                    for (int kk = 0; kk < 4; ++kk)
                        acc = __builtin_amdgcn_mfma_f32_16x16x32_bf16(
                            af[rt][kk], bw[ti][kk], acc, 0, 0, 0);
                    acc2[ti][rt] = acc;
                }
            __syncthreads();   // all af reads done before overwrite
#pragma unroll
            for (int ti = 0; ti < 2; ++ti) {
                int col = (2 * w + ti) * 16 + c16;
                float bias = b1[l * 128 + col];
#pragma unroll
                for (int rt = 0; rt < 2; ++rt)
#pragma unroll
                    for (int r = 0; r < 4; ++r)
                        a_bf[rt * 16 + row4 + r][col] =
                            f2bf(fmaxf(acc2[ti][rt][r] + bias, 0.f));
            }
        }
        __syncthreads();

        // ---- FF2 + residual (registers) ----
        {
            bf16x8 af[2][4];
#pragma unroll
            for (int rt = 0; rt < 2; ++rt)
#pragma unroll
                for (int kk = 0; kk < 4; ++kk)
                    af[rt][kk] = *(const bf16x8*)&a_bf[rt * 16 + c16][kk * 32 + kblk];
            const bf16x8* B = WP + PK_W2(l);
            bf16x8 bw[2][4];
#pragma unroll
            for (int ti = 0; ti < 2; ++ti)
#pragma unroll
                for (int kk = 0; kk < 4; ++kk)
                    bw[ti][kk] = B[((2 * w + ti) * 4 + kk) * 64 + lane];
#pragma unroll
            for (int ti = 0; ti < 2; ++ti) {
                int col = (2 * w + ti) * 16 + c16;
                float bias = b2[l * 128 + col];
#pragma unroll
                for (int rt = 0; rt < 2; ++rt) {
                    f32x4 acc = z4;
#pragma unroll
                    for (int kk = 0; kk < 4; ++kk)
                        acc = __builtin_amdgcn_mfma_f32_16x16x32_bf16(
                            af[rt][kk], bw[ti][kk], acc, 0, 0, 0);
#pragma unroll
                    for (int r = 0; r < 4; ++r)
                        res[rt][ti][r] += acc[r] + bias;
                }
            }
        }
        layer_norm_reg(res, lnG[l][1], lnB[l][1], a_bf, psum, psq, w, c16, row4);
        __syncthreads();
    }

    // ---- masked mean pool (from registers) -> pooled bf16 ----
#pragma unroll
    for (int rt = 0; rt < 2; ++rt) {
        int len = rt ? len1 : len0;
        float fln = (float)len;
#pragma unroll
        for (int ti = 0; ti < 2; ++ti) {
            float s = 0.f;
#pragma unroll
            for (int r = 0; r < 4; ++r)
                if (row4 + r < len) s += res[rt][ti][r];
            s += __shfl_xor(s, 16);
            s += __shfl_xor(s, 32);
            if (lane < 16)
                pooled[(e0 + rt) * 128 + w * 32 + ti * 16 + c16] = f2bf(s / fln);
        }
    }
}

// ---------------------------------------------------------------------------
// Edge-out: m = relu(concat(h[src], pooled) @ W_eout + b_eout), 16 edges/blk,
// atomic scatter into h_agg.
// ---------------------------------------------------------------------------
__global__ __launch_bounds__(256) void edge_out_kernel(
    const float* __restrict__ node_features,
    const int* __restrict__ src_ids, const int* __restrict__ dst_ids,
    const unsigned short* __restrict__ pooled,
    const unsigned short* __restrict__ wpack,
    const float* __restrict__ b_eout,
    float* __restrict__ h_agg)
{
    __shared__ __align__(16) unsigned short a2[16][264];
    __shared__ int dst_s[16];
    const int tid = threadIdx.x, lane = tid & 63, w = tid >> 6;
    const int e0 = blockIdx.x * 16;

    {
        int r = tid >> 4, cm = tid & 15;
        int e = e0 + r;
        int src = src_ids[e];
#pragma unroll
        for (int m = 0; m < 8; ++m) {
            int col = cm + 16 * m;
            a2[r][col] = f2bf(node_features[src * 128 + col]);
        }
#pragma unroll
        for (int m = 0; m < 8; ++m) {
            int col = cm + 16 * m;
            a2[r][128 + col] = pooled[e * 128 + col];
        }
        if (tid < 16) dst_s[tid] = dst_ids[e0 + tid];
    }
    __syncthreads();

    const int c16 = lane & 15, row4 = (lane >> 4) << 2, kblk = (lane >> 4) << 3;
    bf16x8 af[8];
#pragma unroll
    for (int kk = 0; kk < 8; ++kk)
        af[kk] = *(const bf16x8*)&a2[c16][kk * 32 + kblk];
    const bf16x8* B = (const bf16x8*)wpack + PK_WEOUT;
#pragma unroll
    for (int ti = 0; ti < 2; ++ti) {
        int t = w * 2 + ti;
        f32x4 acc = {0.f, 0.f, 0.f, 0.f};
#pragma unroll
        for (int kk = 0; kk < 8; ++kk)
            acc = __builtin_amdgcn_mfma_f32_16x16x32_bf16(
                af[kk], B[(t * 8 + kk) * 64 + lane], acc, 0, 0, 0);
        int col = t * 16 + c16;
        float bias = b_eout[col];
#pragma unroll
        for (int r = 0; r < 4; ++r) {
            int row = row4 + r;
            float v = fmaxf(acc[r] + bias, 0.f);
            atomicAdd(&h_agg[dst_s[row] * 128 + col], v);
        }
    }
}

// ---------------------------------------------------------------------------
// Node update: one block (128 threads) per destination node.
// ---------------------------------------------------------------------------
__global__ __launch_bounds__(128) void node_kernel(
    const float* __restrict__ node_features,
    const int*   __restrict__ layer_nid,
    const float* __restrict__ subg_norm,
    const float* __restrict__ h_agg,
    const float* __restrict__ W_eout, const float* __restrict__ b_eout,
    const float* __restrict__ W_node, const float* __restrict__ b_node,
    const float* __restrict__ W_fc,   const float* __restrict__ b_fc,
    float* __restrict__ out)
{
    __shared__ float sh[128];
    __shared__ float hh[128];
    __shared__ float z[128];

    const int n   = blockIdx.x;
    const int tid = threadIdx.x;
    const int nid = layer_nid[n];
    const float norm = subg_norm[n];

    sh[tid] = node_features[nid * 128 + tid];
    __syncthreads();

    float acc = 0.f;
#pragma unroll 4
    for (int k = 0; k < 128; ++k)
        acc = fmaf(sh[k], W_eout[k * 128 + tid], acc);
    acc += b_eout[tid];
    hh[tid] = (h_agg[n * 128 + tid] - acc) * norm;
    __syncthreads();

    float za = 0.f;
#pragma unroll 4
    for (int k = 0; k < 128; ++k)
        za = fmaf(sh[k], W_node[k * 128 + tid], za);
#pragma unroll 4
    for (int k = 0; k < 128; ++k)
        za = fmaf(hh[k], W_node[(128 + k) * 128 + tid], za);
    za += b_node[tid];
    z[tid] = fmaxf(za, 0.f);
    __syncthreads();

    if (tid < NCLS) {
        float o = 0.f;
#pragma unroll 4
        for (int k = 0; k < 128; ++k)
            o = fmaf(z[k], W_fc[k * NCLS + tid], o);
        out[n * NCLS + tid] = o + b_fc[tid];
    }
}

// ---------------------------------------------------------------------------

extern "C" void kernel_launch(void* const* d_in, const int* in_sizes, int n_in,
                              void* d_out, int out_size, void* d_ws, size_t ws_size,
                              hipStream_t stream) {
    const float* node_features = (const float*)d_in[0];
    const float* edge_features = (const float*)d_in[1];
    const float* seq_times     = (const float*)d_in[2];
    const int*   e_len         = (const int*)d_in[3];
    // d_in[4] = e_mask (recomputed from e_len)
    const int*   src_ids       = (const int*)d_in[5];
    const int*   dst_ids       = (const int*)d_in[6];
    const int*   layer_nid     = (const int*)d_in[7];
    const float* subg_norm     = (const float*)d_in[8];
    const float* W_ein  = (const float*)d_in[9];
    const float* b_ein  = (const float*)d_in[10];
    const float* Wqkv   = (const float*)d_in[11];
    const float* bqkv   = (const float*)d_in[12];
    const float* Wo     = (const float*)d_in[13];
    const float* bo     = (const float*)d_in[14];
    const float* ln1_g  = (const float*)d_in[15];
    const float* ln1_b  = (const float*)d_in[16];
    const float* W1     = (const float*)d_in[17];
    const float* b1     = (const float*)d_in[18];
    const float* W2     = (const float*)d_in[19];
    const float* b2     = (const float*)d_in[20];
    const float* ln2_g  = (const float*)d_in[21];
    const float* ln2_b  = (const float*)d_in[22];
    const float* W_eout = (const float*)d_in[23];
    const float* b_eout = (const float*)d_in[24];
    const float* W_node = (const float*)d_in[25];
    const float* b_node = (const float*)d_in[26];
    const float* W_fc   = (const float*)d_in[27];
    const float* b_fc   = (const float*)d_in[28];

    float*          h_agg  = (float*)((char*)d_ws + OFF_HAGG);
    unsigned short* pooled = (unsigned short*)((char*)d_ws + OFF_POOL);
    unsigned short* wpack  = (unsigned short*)((char*)d_ws + OFF_WPACK);

    pack_weights<<<912, 256, 0, stream>>>(Wqkv, Wo, W1, W2, W_eout, W_ein, wpack);
    hipMemsetAsync(h_agg, 0, (size_t)N_DST_N * 128 * sizeof(float), stream);

    edge_kernel<<<E_N / 2, 256, 0, stream>>>(
        edge_features, seq_times, e_len,
        b_ein, bqkv, bo, ln1_g, ln1_b, b1, b2, ln2_g, ln2_b,
        wpack, pooled);

    edge_out_kernel<<<E_N / 16, 256, 0, stream>>>(
        node_features, src_ids, dst_ids, pooled, wpack, b_eout, h_agg);

    node_kernel<<<N_DST_N, 128, 0, stream>>>(
        node_features, layer_nid, subg_norm, h_agg,
        W_eout, b_eout, W_node, b_node, W_fc, b_fc, (float*)d_out);
}

// Round 6
// 789.736 us; speedup vs baseline: 1.1772x; 1.1772x over previous
//
#include <hip/hip_runtime.h>
#include <hip/hip_bf16.h>

typedef __attribute__((ext_vector_type(8))) short bf16x8;
typedef __attribute__((ext_vector_type(4))) short s16x4;
typedef __attribute__((ext_vector_type(4))) float f32x4;

#define E_N      32768
#define N_DST_N  5000
#define NCLS     10

// ---- workspace layout (bytes) ----
#define OFF_HAGG   0            // f32 [5000][128]
#define OFF_POOL   2560000      // bf16 [32768][128]
#define OFF_WPACK  10948608     // bf16 packed fragments, 233472 elems

// packed-weight offsets in bf16x8 (8-elem) units
#define PK_QKV(l)  ((l) * 6144)
#define PK_WO(l)   (12288 + (l) * 2048)
#define PK_W1(l)   (16384 + (l) * 2048)
#define PK_W2(l)   (20480 + (l) * 2048)
#define PK_WEOUT   24576
#define PK_WEIN    28672

// HW bf16 converts (RNE).
__device__ __forceinline__ unsigned short f2bf(float f) {
    __hip_bfloat16 h = __float2bfloat16(f);
    unsigned short u;
    __builtin_memcpy(&u, &h, 2);
    return u;
}
__device__ __forceinline__ unsigned int f2bf2(float lo, float hi) {
    __hip_bfloat162 h = __float22bfloat162_rn(make_float2(lo, hi));
    unsigned int u;
    __builtin_memcpy(&u, &h, 4);
    return u;
}

// ---------------------------------------------------------------------------
// Pack weights into bf16 B-fragment order:
// dst[((t*(K/32)+kk)*64 + lane)*8 + j] = W[k][n],
//   n = t*16 + (lane&15), k = kk*32 + (lane>>4)*8 + j.
// W_ein packed in a K=32 frame with zeros for k>=16.
// ---------------------------------------------------------------------------
__global__ void pack_weights(const float* __restrict__ Wqkv,
                             const float* __restrict__ Wo,
                             const float* __restrict__ W1,
                             const float* __restrict__ W2,
                             const float* __restrict__ W_eout,
                             const float* __restrict__ W_ein,
                             unsigned short* __restrict__ wpack) {
    int gid = blockIdx.x * 256 + threadIdx.x;
    if (gid >= 233472) return;
    if (gid >= 229376) {                     // W_ein section (K=16 padded to 32)
        int li = gid - 229376;
        int j = li & 7, lane = (li >> 3) & 63, t = li >> 9;
        int k = ((lane >> 4) << 3) + j;
        int n = t * 16 + (lane & 15);
        wpack[gid] = (k < 16) ? f2bf(W_ein[k * 128 + n]) : (unsigned short)0;
        return;
    }
    int id = gid;
    const float* src; int K, N, li;
    if (id < 98304)       { src = Wqkv + (id / 49152) * 49152; li = id % 49152; K = 128; N = 384; }
    else if (id < 131072) { id -= 98304;  src = Wo + (id / 16384) * 16384; li = id % 16384; K = 128; N = 128; }
    else if (id < 163840) { id -= 131072; src = W1 + (id / 16384) * 16384; li = id % 16384; K = 128; N = 128; }
    else if (id < 196608) { id -= 163840; src = W2 + (id / 16384) * 16384; li = id % 16384; K = 128; N = 128; }
    else                  { li = id - 196608; src = W_eout; K = 256; N = 128; }
    int j = li & 7, lane = (li >> 3) & 63, rest = li >> 9;
    int ks = K >> 5;
    int kk = rest % ks, t = rest / ks;
    int k = kk * 32 + ((lane >> 4) << 3) + j;
    int n = t * 16 + (lane & 15);
    wpack[gid] = f2bf(src[k * N + n]);
}

// ---------------------------------------------------------------------------
// LayerNorm over register residual (C-layout). Thread owns cols
// cA=w*32+c16, cB=cA+16, rows {rt*16 + row4 + r}. In-wave shfl reduce over
// c16, cross-wave via psum/psq partial tables. Writes bf16 a_bf mirror.
// Contains one internal __syncthreads (all threads must call).
// ---------------------------------------------------------------------------
__device__ __forceinline__ void layer_norm_reg(
    float res[2][2][4],
    const float gcol[2], const float bcol[2],
    unsigned short (*a_bf)[136],
    float (*psum)[4], float (*psq)[4],
    int w, int c16, int row4)
{
    float sv[2][4], qv[2][4];
#pragma unroll
    for (int rt = 0; rt < 2; ++rt)
#pragma unroll
        for (int r = 0; r < 4; ++r) {
            float x0 = res[rt][0][r], x1 = res[rt][1][r];
            float s = x0 + x1;
            float q = x0 * x0 + x1 * x1;
#pragma unroll
            for (int d = 1; d < 16; d <<= 1) {
                s += __shfl_xor(s, d);
                q += __shfl_xor(q, d);
            }
            sv[rt][r] = s; qv[rt][r] = q;
        }
    if (c16 == 0) {
#pragma unroll
        for (int rt = 0; rt < 2; ++rt)
#pragma unroll
            for (int r = 0; r < 4; ++r) {
                int row = rt * 16 + row4 + r;
                psum[row][w] = sv[rt][r];
                psq[row][w]  = qv[rt][r];
            }
    }
    __syncthreads();
#pragma unroll
    for (int rt = 0; rt < 2; ++rt)
#pragma unroll
        for (int r = 0; r < 4; ++r) {
            int row = rt * 16 + row4 + r;
            float4 S = *(const float4*)&psum[row][0];
            float4 Q = *(const float4*)&psq[row][0];
            float sum = (S.x + S.y) + (S.z + S.w);
            float sq  = (Q.x + Q.y) + (Q.z + Q.w);
            float mu  = sum * (1.f / 128.f);
            float var = sq * (1.f / 128.f) - mu * mu;
            float inv = rsqrtf(var + 1e-5f);
#pragma unroll
            for (int ti = 0; ti < 2; ++ti) {
                float y = (res[rt][ti][r] - mu) * inv * gcol[ti] + bcol[ti];
                res[rt][ti][r] = y;
                a_bf[row][w * 32 + ti * 16 + c16] = f2bf(y);
            }
        }
}

// ---------------------------------------------------------------------------
// Edge mega-kernel: one block (4 waves) per TWO edges. All matmuls AND
// attention on MFMA; residual stream in registers; LN via shfl+partials.
// LDS 39.4 KB -> 4 blocks/CU; launch_bounds(256,4) -> VGPR cap 128, NO SPILL
// (R5 lesson: (256,5) capped to <80 and scratch traffic dominated).
// Separate q_bf removes 2 intra-phase barriers per layer.
// ---------------------------------------------------------------------------
__global__ __launch_bounds__(256, 4) void edge_kernel(
    const float* __restrict__ edge_features,   // [E,16,15]
    const float* __restrict__ seq_times,       // [E,16]
    const int*   __restrict__ e_len,
    const float* __restrict__ b_ein,
    const float* __restrict__ bqkv,  const float* __restrict__ bo,
    const float* __restrict__ ln1_g, const float* __restrict__ ln1_b,
    const float* __restrict__ b1,    const float* __restrict__ b2,
    const float* __restrict__ ln2_g, const float* __restrict__ ln2_b,
    const unsigned short* __restrict__ wpack,
    unsigned short* __restrict__ pooled)       // [E,128] bf16
{
    __shared__ __align__(16) unsigned short a_bf[32][136];  // LN-out / ctx
    __shared__ __align__(16) unsigned short q_bf[32][136];  // Q / FF1-out
    __shared__ __align__(16) unsigned short k_bf[32][136];  // K
    __shared__ __align__(16) union VX {                     // x_bf dead after embed
        unsigned short vT[2][128][24];                      // V transposed [d][s]
        unsigned short x_bf[32][40];                        // input, cols16..31 = 0
    } vx;
    __shared__ __align__(16) float psum[32][4];
    __shared__ __align__(16) float psq[32][4];

    const int tid  = threadIdx.x;
    const int e0   = blockIdx.x * 2;
    const int lane = tid & 63;
    const int w    = tid >> 6;
    const int c16  = lane & 15;
    const int g    = lane >> 4;
    const int row4 = g << 2;
    const int kblk = g << 3;
    const int len0 = e_len[e0];
    const int len1 = e_len[e0 + 1];
    const f32x4 z4 = {0.f, 0.f, 0.f, 0.f};

    float res[2][2][4];          // [edge rt][col ti][row r]

    // LN params for this thread's two columns
    float lnG[2][2][2], lnB[2][2][2];    // [layer][ln#][ti]
#pragma unroll
    for (int l = 0; l < 2; ++l)
#pragma unroll
        for (int ti = 0; ti < 2; ++ti) {
            int col = w * 32 + ti * 16 + c16;
            lnG[l][0][ti] = ln1_g[l * 128 + col];
            lnB[l][0][ti] = ln1_b[l * 128 + col];
            lnG[l][1][ti] = ln2_g[l * 128 + col];
            lnB[l][1][ti] = ln2_b[l * 128 + col];
        }

    // ---- stage input (cols 16..31 zeroed for K=32 padding) ----
    for (int idx = tid; idx < 1024; idx += 256) {
        int r = idx >> 5, cc = idx & 31;
        int e = r >> 4, s = r & 15;
        float v = 0.f;
        if (cc < 15)       v = edge_features[(e0 + e) * 240 + s * 15 + cc];
        else if (cc == 15) v = seq_times[(e0 + e) * 16 + s];
        vx.x_bf[r][cc] = f2bf(v);
    }
    __syncthreads();

    const bf16x8* WP = (const bf16x8*)wpack;

    // ---- embed: relu(x @ W_ein + b) via MFMA (K=16 padded to 32) ----
    {
        bf16x8 axf[2];
#pragma unroll
        for (int rt = 0; rt < 2; ++rt)
            axf[rt] = *(const bf16x8*)&vx.x_bf[rt * 16 + c16][kblk];
#pragma unroll
        for (int ti = 0; ti < 2; ++ti) {
            bf16x8 bw = WP[PK_WEIN + (2 * w + ti) * 64 + lane];
            int col = (2 * w + ti) * 16 + c16;
            float bias = b_ein[col];
#pragma unroll
            for (int rt = 0; rt < 2; ++rt) {
                f32x4 acc = __builtin_amdgcn_mfma_f32_16x16x32_bf16(axf[rt], bw, z4, 0, 0, 0);
#pragma unroll
                for (int r = 0; r < 4; ++r) {
                    float v = fmaxf(acc[r] + bias, 0.f);
                    res[rt][ti][r] = v;
                    a_bf[rt * 16 + row4 + r][col] = f2bf(v);
                }
            }
        }
    }
    __syncthreads();

    for (int l = 0; l < 2; ++l) {
        // ---- QKV: Q -> q_bf, K -> k_bf, V -> vT (no internal barrier) ----
        {
            bf16x8 af[2][4];
#pragma unroll
            for (int rt = 0; rt < 2; ++rt)
#pragma unroll
                for (int kk = 0; kk < 4; ++kk)
                    af[rt][kk] = *(const bf16x8*)&a_bf[rt * 16 + c16][kk * 32 + kblk];
            const bf16x8* B = WP + PK_QKV(l);
#pragma unroll
            for (int seg = 0; seg < 3; ++seg) {
                bf16x8 bq[2][4];
#pragma unroll
                for (int ti = 0; ti < 2; ++ti)
#pragma unroll
                    for (int kk = 0; kk < 4; ++kk)
                        bq[ti][kk] = B[((seg * 8 + 2 * w + ti) * 4 + kk) * 64 + lane];
#pragma unroll
                for (int ti = 0; ti < 2; ++ti) {
                    int col = (2 * w + ti) * 16 + c16;
                    float bias = bqkv[l * 384 + seg * 128 + col];
#pragma unroll
                    for (int rt = 0; rt < 2; ++rt) {
                        f32x4 acc = z4;
#pragma unroll
                        for (int kk = 0; kk < 4; ++kk)
                            acc = __builtin_amdgcn_mfma_f32_16x16x32_bf16(
                                af[rt][kk], bq[ti][kk], acc, 0, 0, 0);
                        if (seg == 0) {
#pragma unroll
                            for (int r = 0; r < 4; ++r)
                                q_bf[rt * 16 + row4 + r][col] = f2bf(acc[r] + bias);
                        } else if (seg == 1) {
#pragma unroll
                            for (int r = 0; r < 4; ++r)
                                k_bf[rt * 16 + row4 + r][col] = f2bf(acc[r] + bias);
                        } else {
                            union { unsigned int u[2]; s16x4 v; } pk;
                            pk.u[0] = f2bf2(acc[0] + bias, acc[1] + bias);
                            pk.u[1] = f2bf2(acc[2] + bias, acc[3] + bias);
                            *(s16x4*)&vx.vT[rt][col][row4] = pk.v;   // V^T[d][s]
                        }
                    }
                }
            }
        }
        __syncthreads();

        // ---- attention via MFMA: S^T = K@Q^T, ctx^T = V^T@P^T ----
#pragma unroll
        for (int i = 0; i < 4; ++i) {
            int pp = w * 4 + i;
            int e  = pp >> 3;
            int hb = (pp & 7) * 16;
            int er = e * 16;
            int len = e ? len1 : len0;
            bf16x8 kf = {0,0,0,0,0,0,0,0};
            bf16x8 qf = {0,0,0,0,0,0,0,0};
            bf16x8 vf = {0,0,0,0,0,0,0,0};
            if (lane < 32) {   // dh = kblk+j < 16 only
                kf = *(const bf16x8*)&k_bf[er + c16][hb + kblk];
                qf = *(const bf16x8*)&q_bf[er + c16][hb + kblk];
                vf = *(const bf16x8*)&vx.vT[e][hb + c16][kblk];
            }
            f32x4 st = __builtin_amdgcn_mfma_f32_16x16x32_bf16(kf, qf, z4, 0, 0, 0);
            // lane holds S^T[k=4g+r][q=c16]
            float sv[4]; float mx = -1e30f;
#pragma unroll
            for (int r = 0; r < 4; ++r) {
                sv[r] = st[r] * 0.25f;
                if (4 * g + r < len) mx = fmaxf(mx, sv[r]);
            }
            mx = fmaxf(mx, __shfl_xor(mx, 16));
            mx = fmaxf(mx, __shfl_xor(mx, 32));
            float p[4]; float sum = 0.f;
#pragma unroll
            for (int r = 0; r < 4; ++r) {
                float pe = (4 * g + r < len) ? __expf(sv[r] - mx) : 0.f;
                p[r] = pe; sum += pe;
            }
            sum += __shfl_xor(sum, 16);
            sum += __shfl_xor(sum, 32);
            float inv = __fdividef(1.f, sum);
            unsigned int own0 = f2bf2(p[0] * inv, p[1] * inv);
            unsigned int own1 = f2bf2(p[2] * inv, p[3] * inv);
            // regroup P^T (C-layout, 4 k/lane) into B-frag layout (8 k/lane)
            unsigned int t0a = (unsigned int)__shfl((int)own0, (lane + 16) & 63);
            unsigned int t1a = (unsigned int)__shfl((int)own1, (lane + 16) & 63);
            unsigned int t0b = (unsigned int)__shfl((int)own0, (lane + 32) & 63);
            unsigned int t1b = (unsigned int)__shfl((int)own1, (lane + 32) & 63);
            union { unsigned int u[4]; bf16x8 v; } pb;
            if (g == 0)      { pb.u[0] = own0; pb.u[1] = own1; pb.u[2] = t0a; pb.u[3] = t1a; }
            else if (g == 1) { pb.u[0] = t0a;  pb.u[1] = t1a;  pb.u[2] = t0b; pb.u[3] = t1b; }
            else             { pb.u[0] = 0; pb.u[1] = 0; pb.u[2] = 0; pb.u[3] = 0; }
            f32x4 ct = __builtin_amdgcn_mfma_f32_16x16x32_bf16(vf, pb.v, z4, 0, 0, 0);
            // lane holds ctx^T[d=4g+r][q=c16] -> a_bf[er+q][hb+4g+r]
            union { unsigned int u[2]; s16x4 v; } cpk;
            cpk.u[0] = f2bf2(ct[0], ct[1]);
            cpk.u[1] = f2bf2(ct[2], ct[3]);
            *(s16x4*)&a_bf[er + c16][hb + 4 * g] = cpk.v;
        }
        __syncthreads();

        // ---- proj + residual (registers) ----
        {
            bf16x8 af[2][4];
#pragma unroll
            for (int rt = 0; rt < 2; ++rt)
#pragma unroll
                for (int kk = 0; kk < 4; ++kk)
                    af[rt][kk] = *(const bf16x8*)&a_bf[rt * 16 + c16][kk * 32 + kblk];
            const bf16x8* B = WP + PK_WO(l);
            bf16x8 bw[2][4];
#pragma unroll
            for (int ti = 0; ti < 2; ++ti)
#pragma unroll
                for (int kk = 0; kk < 4; ++kk)
                    bw[ti][kk] = B[((2 * w + ti) * 4 + kk) * 64 + lane];
#pragma unroll
            for (int ti = 0; ti < 2; ++ti) {
                int col = (2 * w + ti) * 16 + c16;
                float bias = bo[l * 128 + col];
#pragma unroll
                for (int rt = 0; rt < 2; ++rt) {
                    f32x4 acc = z4;
#pragma unroll
                    for (int kk = 0; kk < 4; ++kk)
                        acc = __builtin_amdgcn_mfma_f32_16x16x32_bf16(
                            af[rt][kk], bw[ti][kk], acc, 0, 0, 0);
#pragma unroll
                    for (int r = 0; r < 4; ++r)
                        res[rt][ti][r] += acc[r] + bias;
                }
            }
        }
        layer_norm_reg(res, lnG[l][0], lnB[l][0], a_bf, psum, psq, w, c16, row4);
        __syncthreads();

        // ---- FF1: relu(e @ W1 + b1) -> q_bf (no internal barrier) ----
        {
            bf16x8 af[2][4];
#pragma unroll
            for (int rt = 0; rt < 2; ++rt)
#pragma unroll
                for (int kk = 0; kk < 4; ++kk)
                    af[rt][kk] = *(const bf16x8*)&a_bf[rt * 16 + c16][kk * 32 + kblk];
            const bf16x8* B = WP + PK_W1(l);
            bf16x8 bw[2][4];
#pragma unroll
            for (int ti = 0; ti < 2; ++ti)
#pragma unroll
                for (int kk = 0; kk < 4; ++kk)
                    bw[ti][kk] = B[((2 * w + ti) * 4 + kk) * 64 + lane];
#pragma unroll
            for (int ti = 0; ti < 2; ++ti) {
                int col = (2 * w + ti) * 16 + c16;
                float bias = b1[l * 128 + col];
#pragma unroll
                for (int rt = 0; rt < 2; ++rt) {
                    f32x4 acc = z4;
#pragma unroll
                    for (int kk = 0; kk < 4; ++kk)
                        acc = __builtin_amdgcn_mfma_f32_16x16x32_bf16(
                            af[rt][kk], bw[ti][kk], acc, 0, 0, 0);
#pragma unroll
                    for (int r = 0; r < 4; ++r)
                        q_bf[rt * 16 + row4 + r][col] =
                            f2bf(fmaxf(acc[r] + bias, 0.f));
                }
            }
        }
        __syncthreads();

        // ---- FF2 + residual (registers): reads q_bf ----
        {
            bf16x8 af[2][4];
#pragma unroll
            for (int rt = 0; rt < 2; ++rt)
#pragma unroll
                for (int kk = 0; kk < 4; ++kk)
                    af[rt][kk] = *(const bf16x8*)&q_bf[rt * 16 + c16][kk * 32 + kblk];
            const bf16x8* B = WP + PK_W2(l);
            bf16x8 bw[2][4];
#pragma unroll
            for (int ti = 0; ti < 2; ++ti)
#pragma unroll
                for (int kk = 0; kk < 4; ++kk)
                    bw[ti][kk] = B[((2 * w + ti) * 4 + kk) * 64 + lane];
#pragma unroll
            for (int ti = 0; ti < 2; ++ti) {
                int col = (2 * w + ti) * 16 + c16;
                float bias = b2[l * 128 + col];
#pragma unroll
                for (int rt = 0; rt < 2; ++rt) {
                    f32x4 acc = z4;
#pragma unroll
                    for (int kk = 0; kk < 4; ++kk)
                        acc = __builtin_amdgcn_mfma_f32_16x16x32_bf16(
                            af[rt][kk], bw[ti][kk], acc, 0, 0, 0);
#pragma unroll
                    for (int r = 0; r < 4; ++r)
                        res[rt][ti][r] += acc[r] + bias;
                }
            }
        }
        layer_norm_reg(res, lnG[l][1], lnB[l][1], a_bf, psum, psq, w, c16, row4);
        __syncthreads();
    }

    // ---- masked mean pool (from registers) -> pooled bf16 ----
#pragma unroll
    for (int rt = 0; rt < 2; ++rt) {
        int len = rt ? len1 : len0;
        float fln = (float)len;
#pragma unroll
        for (int ti = 0; ti < 2; ++ti) {
            float s = 0.f;
#pragma unroll
            for (int r = 0; r < 4; ++r)
                if (row4 + r < len) s += res[rt][ti][r];
            s += __shfl_xor(s, 16);
            s += __shfl_xor(s, 32);
            if (lane < 16)
                pooled[(e0 + rt) * 128 + w * 32 + ti * 16 + c16] = f2bf(s / fln);
        }
    }
}

// ---------------------------------------------------------------------------
// Edge-out: m = relu(concat(h[src], pooled) @ W_eout + b_eout), 16 edges/blk,
// atomic scatter into h_agg.
// ---------------------------------------------------------------------------
__global__ __launch_bounds__(256) void edge_out_kernel(
    const float* __restrict__ node_features,
    const int* __restrict__ src_ids, const int* __restrict__ dst_ids,
    const unsigned short* __restrict__ pooled,
    const unsigned short* __restrict__ wpack,
    const float* __restrict__ b_eout,
    float* __restrict__ h_agg)
{
    __shared__ __align__(16) unsigned short a2[16][264];
    __shared__ int dst_s[16];
    const int tid = threadIdx.x, lane = tid & 63, w = tid >> 6;
    const int e0 = blockIdx.x * 16;

    {
        int r = tid >> 4, cm = tid & 15;
        int e = e0 + r;
        int src = src_ids[e];
#pragma unroll
        for (int m = 0; m < 8; ++m) {
            int col = cm + 16 * m;
            a2[r][col] = f2bf(node_features[src * 128 + col]);
        }
#pragma unroll
        for (int m = 0; m < 8; ++m) {
            int col = cm + 16 * m;
            a2[r][128 + col] = pooled[e * 128 + col];
        }
        if (tid < 16) dst_s[tid] = dst_ids[e0 + tid];
    }
    __syncthreads();

    const int c16 = lane & 15, row4 = (lane >> 4) << 2, kblk = (lane >> 4) << 3;
    bf16x8 af[8];
#pragma unroll
    for (int kk = 0; kk < 8; ++kk)
        af[kk] = *(const bf16x8*)&a2[c16][kk * 32 + kblk];
    const bf16x8* B = (const bf16x8*)wpack + PK_WEOUT;
#pragma unroll
    for (int ti = 0; ti < 2; ++ti) {
        int t = w * 2 + ti;
        f32x4 acc = {0.f, 0.f, 0.f, 0.f};
#pragma unroll
        for (int kk = 0; kk < 8; ++kk)
            acc = __builtin_amdgcn_mfma_f32_16x16x32_bf16(
                af[kk], B[(t * 8 + kk) * 64 + lane], acc, 0, 0, 0);
        int col = t * 16 + c16;
        float bias = b_eout[col];
#pragma unroll
        for (int r = 0; r < 4; ++r) {
            int row = row4 + r;
            float v = fmaxf(acc[r] + bias, 0.f);
            atomicAdd(&h_agg[dst_s[row] * 128 + col], v);
        }
    }
}

// ---------------------------------------------------------------------------
// Node update: one block (128 threads) per destination node.
// ---------------------------------------------------------------------------
__global__ __launch_bounds__(128) void node_kernel(
    const float* __restrict__ node_features,
    const int*   __restrict__ layer_nid,
    const float* __restrict__ subg_norm,
    const float* __restrict__ h_agg,
    const float* __restrict__ W_eout, const float* __restrict__ b_eout,
    const float* __restrict__ W_node, const float* __restrict__ b_node,
    const float* __restrict__ W_fc,   const float* __restrict__ b_fc,
    float* __restrict__ out)
{
    __shared__ float sh[128];
    __shared__ float hh[128];
    __shared__ float z[128];

    const int n   = blockIdx.x;
    const int tid = threadIdx.x;
    const int nid = layer_nid[n];
    const float norm = subg_norm[n];

    sh[tid] = node_features[nid * 128 + tid];
    __syncthreads();

    float acc = 0.f;
#pragma unroll 4
    for (int k = 0; k < 128; ++k)
        acc = fmaf(sh[k], W_eout[k * 128 + tid], acc);
    acc += b_eout[tid];
    hh[tid] = (h_agg[n * 128 + tid] - acc) * norm;
    __syncthreads();

    float za = 0.f;
#pragma unroll 4
    for (int k = 0; k < 128; ++k)
        za = fmaf(sh[k], W_node[k * 128 + tid], za);
#pragma unroll 4
    for (int k = 0; k < 128; ++k)
        za = fmaf(hh[k], W_node[(128 + k) * 128 + tid], za);
    za += b_node[tid];
    z[tid] = fmaxf(za, 0.f);
    __syncthreads();

    if (tid < NCLS) {
        float o = 0.f;
#pragma unroll 4
        for (int k = 0; k < 128; ++k)
            o = fmaf(z[k], W_fc[k * NCLS + tid], o);
        out[n * NCLS + tid] = o + b_fc[tid];
    }
}

// ---------------------------------------------------------------------------

extern "C" void kernel_launch(void* const* d_in, const int* in_sizes, int n_in,
                              void* d_out, int out_size, void* d_ws, size_t ws_size,
                              hipStream_t stream) {
    const float* node_features = (const float*)d_in[0];
    const float* edge_features = (const float*)d_in[1];
    const float* seq_times     = (const float*)d_in[2];
    const int*   e_len         = (const int*)d_in[3];
    // d_in[4] = e_mask (recomputed from e_len)
    const int*   src_ids       = (const int*)d_in[5];
    const int*   dst_ids       = (const int*)d_in[6];
    const int*   layer_nid     = (const int*)d_in[7];
    const float* subg_norm     = (const float*)d_in[8];
    const float* W_ein  = (const float*)d_in[9];
    const float* b_ein  = (const float*)d_in[10];
    const float* Wqkv   = (const float*)d_in[11];
    const float* bqkv   = (const float*)d_in[12];
    const float* Wo     = (const float*)d_in[13];
    const float* bo     = (const float*)d_in[14];
    const float* ln1_g  = (const float*)d_in[15];
    const float* ln1_b  = (const float*)d_in[16];
    const float* W1     = (const float*)d_in[17];
    const float* b1     = (const float*)d_in[18];
    const float* W2     = (const float*)d_in[19];
    const float* b2     = (const float*)d_in[20];
    const float* ln2_g  = (const float*)d_in[21];
    const float* ln2_b  = (const float*)d_in[22];
    const float* W_eout = (const float*)d_in[23];
    const float* b_eout = (const float*)d_in[24];
    const float* W_node = (const float*)d_in[25];
    const float* b_node = (const float*)d_in[26];
    const float* W_fc   = (const float*)d_in[27];
    const float* b_fc   = (const float*)d_in[28];

    float*          h_agg  = (float*)((char*)d_ws + OFF_HAGG);
    unsigned short* pooled = (unsigned short*)((char*)d_ws + OFF_POOL);
    unsigned short* wpack  = (unsigned short*)((char*)d_ws + OFF_WPACK);

    pack_weights<<<912, 256, 0, stream>>>(Wqkv, Wo, W1, W2, W_eout, W_ein, wpack);
    hipMemsetAsync(h_agg, 0, (size_t)N_DST_N * 128 * sizeof(float), stream);

    edge_kernel<<<E_N / 2, 256, 0, stream>>>(
        edge_features, seq_times, e_len,
        b_ein, bqkv, bo, ln1_g, ln1_b, b1, b2, ln2_g, ln2_b,
        wpack, pooled);

    edge_out_kernel<<<E_N / 16, 256, 0, stream>>>(
        node_features, src_ids, dst_ids, pooled, wpack, b_eout, h_agg);

    node_kernel<<<N_DST_N, 128, 0, stream>>>(
        node_features, layer_nid, subg_norm, h_agg,
        W_eout, b_eout, W_node, b_node, W_fc, b_fc, (float*)d_out);
}